// Round 19
// baseline (318.058 us; speedup 1.0000x reference)
//
#include <hip/hip_runtime.h>
#include <math.h>
#include <float.h>

#define N_NODES 50000
#define N_EDGES 800000
#define D_INP   96
#define D_HID   128
#define N_B     512
#define CAP     64            // bucket capacity; in-degree ~Poisson(16), P(>64)~1e-17
#define XS_LD   100           // padded leading dim (aligned for float4, spreads banks)
#define HLN     160           // LDS-cached h4 nodes per graph (len ~98 +- 10)
#define TAILCAP 64            // global-scratch overflow nodes per graph

typedef __attribute__((ext_vector_type(4))) _Float16 half4;
typedef __attribute__((ext_vector_type(8))) _Float16 half8;

// ---------------------------------------------------------------------------
// Input layer (runs FIRST): h16 = fp16(relu(x @ W_in^T + b_in)).
// Also zeros cnt. W_in transposed in-kernel: coalesced global load into LDS
// scratch, then LDS->LDS transpose (R17 lesson: never uncoalesced global).
__global__ __launch_bounds__(256) void k_ingemm(const float* __restrict__ x,
                                                const float* __restrict__ W_in,
                                                const float* __restrict__ b_in,
                                                _Float16* __restrict__ h16,
                                                int* __restrict__ cnt) {
    int gid = (blockIdx.y * gridDim.x + blockIdx.x) * 256 + threadIdx.x;
    if (gid < N_NODES) cnt[gid] = 0;

    __shared__ __align__(16) float xs[64 * XS_LD];
    __shared__ __align__(16) float ws[96 * 64];
    int n0 = blockIdx.x * 64;
    int d0 = blockIdx.y * 64;
    int tid = threadIdx.x;

    // stage W_in rows d0..d0+63 coalesced into xs (scratch)
    for (int i = tid; i < 64 * 24; i += 256) {
        int row = i / 24, c4 = i % 24;
        float4 v = *(const float4*)&W_in[(size_t)(d0 + row) * 96 + c4 * 4];
        *(float4*)&xs[row * XS_LD + c4 * 4] = v;
    }
    __syncthreads();
    // transpose to ws[k][dd] = W_in[d0+dd][k]
    for (int i = tid; i < 96 * 64; i += 256) {
        int k = i >> 6, dd = i & 63;
        ws[i] = xs[dd * XS_LD + k];
    }
    __syncthreads();
    // now load x tile into xs
    for (int j = tid; j < 64 * 96 / 4; j += 256) {
        int row = (j * 4) / 96, col = (j * 4) % 96;
        int node = n0 + row;
        float4 v = make_float4(0.f, 0.f, 0.f, 0.f);
        if (node < N_NODES) v = *(const float4*)&x[(size_t)node * 96 + col];
        *(float4*)&xs[row * XS_LD + col] = v;
    }
    __syncthreads();

    int tn = tid / 16;
    int td = tid % 16;
    float acc[4][4] = {};
    for (int k0 = 0; k0 < 96; k0 += 4) {
        float4 w0 = *(float4*)&ws[(k0 + 0) * 64 + td * 4];
        float4 w1 = *(float4*)&ws[(k0 + 1) * 64 + td * 4];
        float4 w2 = *(float4*)&ws[(k0 + 2) * 64 + td * 4];
        float4 w3 = *(float4*)&ws[(k0 + 3) * 64 + td * 4];
#pragma unroll
        for (int j = 0; j < 4; j++) {
            float4 xv = *(float4*)&xs[(tn * 4 + j) * XS_LD + k0];
            acc[j][0] += xv.x * w0.x + xv.y * w1.x + xv.z * w2.x + xv.w * w3.x;
            acc[j][1] += xv.x * w0.y + xv.y * w1.y + xv.z * w2.y + xv.w * w3.y;
            acc[j][2] += xv.x * w0.z + xv.y * w1.z + xv.z * w2.z + xv.w * w3.z;
            acc[j][3] += xv.x * w0.w + xv.y * w1.w + xv.z * w2.w + xv.w * w3.w;
        }
    }
    float4 bb = *(const float4*)&b_in[d0 + td * 4];
#pragma unroll
    for (int j = 0; j < 4; j++) {
        int node = n0 + tn * 4 + j;
        if (node < N_NODES) {
            half4 s;
            s.x = (_Float16)fmaxf(acc[j][0] + bb.x, 0.f);
            s.y = (_Float16)fmaxf(acc[j][1] + bb.y, 0.f);
            s.z = (_Float16)fmaxf(acc[j][2] + bb.z, 0.f);
            s.w = (_Float16)fmaxf(acc[j][3] + bb.w, 0.f);
            *(half4*)&h16[(size_t)node * D_HID + d0 + td * 4] = s;
        }
    }
}

// ---------------------------------------------------------------------------
// XCD-partitioned edge bucketing (+ seg_ptr + Wt2 side-duties, absorbing the
// old k_prep). 8 blocks per 256-edge chunk; (blockIdx&7)==j handles edges
// with (dst&7)==j -> each esrc row written by ONE XCD (sector merging).
__global__ void k_bucket8(const int* __restrict__ src, const int* __restrict__ dst,
                          const int* __restrict__ batch,
                          const float* __restrict__ W_ih,
                          const float* __restrict__ W_hh,
                          int* __restrict__ cnt, unsigned short* __restrict__ esrc,
                          int* __restrict__ seg_ptr, float* __restrict__ Wt2) {
    int gid = blockIdx.x * 256 + threadIdx.x;
    if (gid < N_NODES) {
        int n = gid;
        int bc = batch[n];
        int bp = (n == 0) ? -1 : batch[n - 1];
        for (int b = bp + 1; b <= bc; b++) seg_ptr[b] = n;
        if (n == N_NODES - 1)
            for (int b = bc + 1; b <= N_B; b++) seg_ptr[b] = N_NODES;
    }
    if (gid < 256 * 512) {
        int k = gid / 512, g = gid % 512;
        float v = W_ih[g * 256 + k];
        if (k < 128) v += W_hh[g * 128 + k];
        Wt2[gid] = v;
    }
    int chunk = blockIdx.x >> 3;
    int part  = blockIdx.x & 7;
    int e = chunk * 256 + threadIdx.x;
    if (e < N_EDGES) {
        int d = dst[e];
        if ((d & 7) == part) {
            int p = atomicAdd(&cnt[d], 1);
            if (p < CAP) esrc[(size_t)d * CAP + p] = (unsigned short)src[e];
        }
    }
}

// ---------------------------------------------------------------------------
// MPNN step, all-fp16 state (fp32 accumulation): 16-lane groups, half8 gathers.
__global__ __launch_bounds__(256) void k_mpnn(const _Float16* __restrict__ hin16,
                                              _Float16* __restrict__ hout16,
                                              const int* __restrict__ cnt,
                                              const unsigned short* __restrict__ esrc) {
    int g = threadIdx.x >> 4;
    int l = threadIdx.x & 15;
    int n = blockIdx.x * 16 + g;
    if (n >= N_NODES) return;
    int deg = cnt[n];
    int len = min(deg, CAP);
    const unsigned short* row = &esrc[(size_t)n * CAP];
    float a0[8] = {}, a1[8] = {}, a2[8] = {}, a3[8] = {};
    int i = 0;
    for (; i + 4 <= len; i += 4) {
        int e0 = row[i + 0];
        int e1 = row[i + 1];
        int e2 = row[i + 2];
        int e3 = row[i + 3];
        half8 v0 = *(const half8*)&hin16[(size_t)e0 * 128 + l * 8];
        half8 v1 = *(const half8*)&hin16[(size_t)e1 * 128 + l * 8];
        half8 v2 = *(const half8*)&hin16[(size_t)e2 * 128 + l * 8];
        half8 v3 = *(const half8*)&hin16[(size_t)e3 * 128 + l * 8];
#pragma unroll
        for (int c = 0; c < 8; c++) {
            a0[c] += (float)v0[c];
            a1[c] += (float)v1[c];
            a2[c] += (float)v2[c];
            a3[c] += (float)v3[c];
        }
    }
    for (; i < len; i++) {
        int e0 = row[i];
        half8 v0 = *(const half8*)&hin16[(size_t)e0 * 128 + l * 8];
#pragma unroll
        for (int c = 0; c < 8; c++) a0[c] += (float)v0[c];
    }
#pragma unroll
    for (int c = 0; c < 8; c++) a0[c] += a1[c] + a2[c] + a3[c];
    float invd = 1.0f / (float)max(deg, 1);
    half8 sv = *(const half8*)&hin16[(size_t)n * 128 + l * 8];
    half8 s;
#pragma unroll
    for (int c = 0; c < 8; c++)
        s[c] = (_Float16)(((float)sv[c] + a0[c] * invd) * 0.5f);
    *(half8*)&hout16[(size_t)n * 128 + l * 8] = s;
}

__device__ __forceinline__ float sigmoidf_(float v) { return 1.0f / (1.0f + expf(-v)); }

// ---------------------------------------------------------------------------
// Fused MPNN-step-4 + Set2Set + head. 512 blocks (1 graph each) x 512 threads.
// Phase 0 computes this segment's h4 from h3 (global, complete) into LDS fp16;
// the 3 attention passes then read LDS. Kills the h4 global round-trip and
// one dispatch boundary.
__global__ __launch_bounds__(512) void k_s2s3(const float* __restrict__ Wt2,
                                              const float* __restrict__ b_ih,
                                              const float* __restrict__ b_hh,
                                              const _Float16* __restrict__ h3,
                                              const int* __restrict__ cnt,
                                              const unsigned short* __restrict__ esrc,
                                              const int* __restrict__ seg_ptr,
                                              const float* __restrict__ W_pred,
                                              const float* __restrict__ b_pred,
                                              _Float16* __restrict__ tail,
                                              float* __restrict__ out) {
    __shared__ __align__(16) _Float16 hl[HLN * 128];   // 40 KB
    __shared__ __align__(16) float sr_s[32][128];      // 16 KB
    __shared__ __align__(16) float gates_s[512];       // 2 KB
    __shared__ __align__(16) float in_s[256];          // hh(128) | r(128)
    __shared__ __align__(16) float c_s[128];
    __shared__ __align__(16) float bias_s[512];
    __shared__ float smax_s[32];
    __shared__ float ssum_s[32];
    __shared__ float red_s[128];

    int t = threadIdx.x;
    int b = blockIdx.x;
    if (t < 256) in_s[t] = 0.f;
    if (t < 128) c_s[t] = 0.f;
    bias_s[t] = b_ih[t] + b_hh[t];

    int s0 = seg_ptr[b], s1 = seg_ptr[b + 1];
    int len = s1 - s0;
    if (len > HLN + TAILCAP) len = HLN + TAILCAP;   // statistically impossible

    int grp = t >> 4;        // 32 node-groups
    int lane = t & 15;       // 16 lanes x 8 feats

    // ---- phase 0: h4 for this segment -> LDS (tail -> global scratch)
    for (int nl = grp; nl < len; nl += 32) {
        int n = s0 + nl;
        int deg = cnt[n];
        int ln = min(deg, CAP);
        const unsigned short* row = &esrc[(size_t)n * CAP];
        float a0[8] = {}, a1[8] = {}, a2[8] = {}, a3[8] = {};
        int i = 0;
        for (; i + 4 <= ln; i += 4) {
            int e0 = row[i + 0];
            int e1 = row[i + 1];
            int e2 = row[i + 2];
            int e3 = row[i + 3];
            half8 v0 = *(const half8*)&h3[(size_t)e0 * 128 + lane * 8];
            half8 v1 = *(const half8*)&h3[(size_t)e1 * 128 + lane * 8];
            half8 v2 = *(const half8*)&h3[(size_t)e2 * 128 + lane * 8];
            half8 v3 = *(const half8*)&h3[(size_t)e3 * 128 + lane * 8];
#pragma unroll
            for (int c = 0; c < 8; c++) {
                a0[c] += (float)v0[c];
                a1[c] += (float)v1[c];
                a2[c] += (float)v2[c];
                a3[c] += (float)v3[c];
            }
        }
        for (; i < ln; i++) {
            int e0 = row[i];
            half8 v0 = *(const half8*)&h3[(size_t)e0 * 128 + lane * 8];
#pragma unroll
            for (int c = 0; c < 8; c++) a0[c] += (float)v0[c];
        }
#pragma unroll
        for (int c = 0; c < 8; c++) a0[c] += a1[c] + a2[c] + a3[c];
        float invd = 1.0f / (float)max(deg, 1);
        half8 sv = *(const half8*)&h3[(size_t)n * 128 + lane * 8];
        half8 o16;
#pragma unroll
        for (int c = 0; c < 8; c++)
            o16[c] = (_Float16)(((float)sv[c] + a0[c] * invd) * 0.5f);
        if (nl < HLN)
            *(half8*)&hl[nl * 128 + lane * 8] = o16;
        else
            *(half8*)&tail[((size_t)b * TAILCAP + (nl - HLN)) * 128 + lane * 8] = o16;
    }
    __syncthreads();

    // ---- 3 Set2Set steps
    for (int step = 0; step < 3; step++) {
        // gates GEMM: thread t -> gate t (K=256)
        {
            float acc = 0.f;
#pragma unroll 8
            for (int k = 0; k < 256; k++)
                acc += in_s[k] * Wt2[k * 512 + t];
            gates_s[t] = acc + bias_s[t];
        }
        __syncthreads();
        // LSTM
        if (t < 128) {
            float ig = gates_s[t];
            float fg = gates_s[128 + t];
            float gg = gates_s[256 + t];
            float og = gates_s[384 + t];
            float c = sigmoidf_(fg) * c_s[t] + sigmoidf_(ig) * tanhf(gg);
            c_s[t] = c;
            in_s[t] = sigmoidf_(og) * tanhf(c);   // hh (= q)
        }
        __syncthreads();
        // attention over LDS-cached h4 (single online state; chain ~len/32)
        float qr[8];
#pragma unroll
        for (int c = 0; c < 8; c++) qr[c] = in_s[lane * 8 + c];
        float M = -INFINITY, asum = 0.f;
        float racc[8] = {};
        for (int nl = grp; nl < len; nl += 32) {
            half8 hv;
            if (nl < HLN) hv = *(const half8*)&hl[nl * 128 + lane * 8];
            else hv = *(const half8*)&tail[((size_t)b * TAILCAP + (nl - HLN)) * 128 + lane * 8];
            float hf[8];
#pragma unroll
            for (int c = 0; c < 8; c++) hf[c] = (float)hv[c];
            float d = 0.f;
#pragma unroll
            for (int c = 0; c < 8; c++) d += qr[c] * hf[c];
            d += __shfl_xor(d, 8, 64);
            d += __shfl_xor(d, 4, 64);
            d += __shfl_xor(d, 2, 64);
            d += __shfl_xor(d, 1, 64);
            float nM = fmaxf(M, d);
            float sc = expf(M - nM);
            float a = expf(d - nM);
            asum = asum * sc + a;
#pragma unroll
            for (int c = 0; c < 8; c++) racc[c] = racc[c] * sc + a * hf[c];
            M = nM;
        }
        if (lane == 0) { smax_s[grp] = M; ssum_s[grp] = asum; }
#pragma unroll
        for (int c = 0; c < 8; c++) sr_s[grp][lane * 8 + c] = racc[c];
        __syncthreads();
        // merge 32 group-partials; write r; last step also head partials
        if (t < 128) {
            float Mx = -INFINITY;
#pragma unroll
            for (int g = 0; g < 32; g++) Mx = fmaxf(Mx, smax_s[g]);
            float o = 0.f;
            if (Mx > -INFINITY) {
                float tot = 0.f, osum = 0.f;
#pragma unroll
                for (int g = 0; g < 32; g++) {
                    float w = expf(smax_s[g] - Mx);   // -inf -> 0
                    tot += ssum_s[g] * w;
                    osum += sr_s[g][t] * w;
                }
                o = osum / (tot + 1e-16f);
            }
            in_s[128 + t] = o;
            if (step == 2)
                red_s[t] = in_s[t] * W_pred[t] + o * W_pred[128 + t];
        }
        __syncthreads();
    }
    // ---- head reduce
    if (t < 64) {
        float s = red_s[t] + red_s[t + 64];
        for (int m = 32; m >= 1; m >>= 1) s += __shfl_xor(s, m, 64);
        if (t == 0) out[b] = s + b_pred[0];
    }
}

// ---------------------------------------------------------------------------
extern "C" void kernel_launch(void* const* d_in, const int* in_sizes, int n_in,
                              void* d_out, int out_size, void* d_ws, size_t ws_size,
                              hipStream_t stream) {
    const float* x      = (const float*)d_in[0];
    const int*   edge   = (const int*)d_in[1];
    const int*   batch  = (const int*)d_in[2];
    const float* W_in   = (const float*)d_in[3];
    const float* b_in   = (const float*)d_in[4];
    const float* W_ih   = (const float*)d_in[5];
    const float* W_hh   = (const float*)d_in[6];
    const float* b_ih   = (const float*)d_in[7];
    const float* b_hh   = (const float*)d_in[8];
    const float* W_pred = (const float*)d_in[9];
    const float* b_pred = (const float*)d_in[10];
    float* out = (float*)d_out;

    const int* src = edge;
    const int* dst = edge + N_EDGES;

    float* f = (float*)d_ws;
    _Float16* g0 = (_Float16*)f;          f += (size_t)N_NODES * D_HID / 2;
    _Float16* g1 = (_Float16*)f;          f += (size_t)N_NODES * D_HID / 2;
    _Float16* tail = (_Float16*)f;        f += (size_t)N_B * TAILCAP * D_HID / 2;
    float* Wt2   = f;                     f += 256 * 512;
    int* ip = (int*)f;
    int* cnt     = ip;                    ip += N_NODES;
    int* seg_ptr = ip;                    ip += N_B + 1 + 3;   // keep alignment
    unsigned short* esrc = (unsigned short*)ip;   // 50000*64*2 B

    // ---- input layer (zeros cnt; in-kernel W_in transpose)
    k_ingemm<<<dim3((N_NODES + 63) / 64, 2), 256, 0, stream>>>(x, W_in, b_in, g0, cnt);

    // ---- XCD-partitioned edge bucketing (+ seg_ptr + Wt2 side-duties)
    k_bucket8<<<((N_EDGES + 255) / 256) * 8, 256, 0, stream>>>(
        src, dst, batch, W_ih, W_hh, cnt, esrc, seg_ptr, Wt2);

    // ---- 3 MPNN steps (step 4 fused into s2s3): g0->g1->g0->g1 (h3 in g1)
    int mb = (N_NODES + 15) / 16;
    k_mpnn<<<mb, 256, 0, stream>>>(g0, g1, cnt, esrc);
    k_mpnn<<<mb, 256, 0, stream>>>(g1, g0, cnt, esrc);
    k_mpnn<<<mb, 256, 0, stream>>>(g0, g1, cnt, esrc);

    // ---- fused mpnn4 + Set2Set + head
    k_s2s3<<<N_B, 512, 0, stream>>>(Wt2, b_ih, b_hh, g1, cnt, esrc, seg_ptr,
                                    W_pred, b_pred, tail, out);
}

// Round 20
// 315.933 us; speedup vs baseline: 1.0067x; 1.0067x over previous
//
#include <hip/hip_runtime.h>
#include <math.h>
#include <float.h>

#define N_NODES 50000
#define N_EDGES 800000
#define D_INP   96
#define D_HID   128
#define N_B     512
#define CAP     64            // bucket capacity; in-degree ~Poisson(16), P(>64)~1e-17
#define XS_LD   100           // padded leading dim: avoids 4-way LDS conflict

typedef __attribute__((ext_vector_type(4))) _Float16 half4;
typedef __attribute__((ext_vector_type(8))) _Float16 half8;

// ---------------------------------------------------------------------------
// Weight prep + zero cnt + seg_ptr. Separate small kernel (R17/R19 lessons:
// fusing prep into a big kernel costs more than the boundary it saves).
__global__ void k_prep(const float* __restrict__ W_in,
                       const float* __restrict__ W_ih,
                       const float* __restrict__ W_hh,
                       const int* __restrict__ batch,
                       float* __restrict__ Wt_in,
                       float* __restrict__ Wt2,
                       int* __restrict__ cnt,
                       int* __restrict__ seg_ptr) {
    int idx = blockIdx.x * 256 + threadIdx.x;
    if (idx < N_NODES) {
        cnt[idx] = 0;
        int n = idx;
        int bc = batch[n];
        int bp = (n == 0) ? -1 : batch[n - 1];
        for (int b = bp + 1; b <= bc; b++) seg_ptr[b] = n;
        if (n == N_NODES - 1)
            for (int b = bc + 1; b <= N_B; b++) seg_ptr[b] = N_NODES;
    }
    if (idx < D_INP * D_HID) {
        int k = idx / D_HID, d = idx % D_HID;
        Wt_in[idx] = W_in[d * D_INP + k];
    }
    if (idx < 256 * 512) {
        int k = idx / 512, g = idx % 512;
        float v = W_ih[g * 256 + k];
        if (k < 128) v += W_hh[g * 128 + k];
        Wt2[idx] = v;
    }
}

// ---------------------------------------------------------------------------
// XCD-partitioned edge bucketing: 8 blocks per 256-edge chunk; block with
// (blockIdx&7)==j handles only edges with (dst&7)==j -> each esrc row is
// written by ONE XCD, 64B sectors merge in that XCD's L2.
__global__ void k_bucket8(const int* __restrict__ src, const int* __restrict__ dst,
                          int* __restrict__ cnt, unsigned short* __restrict__ esrc) {
    int chunk = blockIdx.x >> 3;
    int part  = blockIdx.x & 7;
    int e = chunk * 256 + threadIdx.x;
    if (e < N_EDGES) {
        int d = dst[e];
        if ((d & 7) == part) {
            int p = atomicAdd(&cnt[d], 1);
            if (p < CAP) esrc[(size_t)d * CAP + p] = (unsigned short)src[e];
        }
    }
}

// ---------------------------------------------------------------------------
// Input layer: h16 = fp16(relu(x @ W_in^T + b_in)); coalesced Wt_in staging.
__global__ __launch_bounds__(256) void k_ingemm(const float* __restrict__ x,
                                                const float* __restrict__ Wt_in,
                                                const float* __restrict__ b_in,
                                                _Float16* __restrict__ h16) {
    __shared__ __align__(16) float xs[64 * XS_LD];
    __shared__ __align__(16) float ws[96 * 64];
    int n0 = blockIdx.x * 64;
    int d0 = blockIdx.y * 64;
    int tid = threadIdx.x;
    for (int j = tid; j < 64 * 96 / 4; j += 256) {
        int row = (j * 4) / 96, col = (j * 4) % 96;
        int node = n0 + row;
        float4 v = make_float4(0.f, 0.f, 0.f, 0.f);
        if (node < N_NODES) v = *(const float4*)&x[(size_t)node * 96 + col];
        *(float4*)&xs[row * XS_LD + col] = v;
    }
    for (int j = tid; j < 96 * 64 / 4; j += 256) {
        int k = (j * 4) / 64, dd = (j * 4) % 64;
        *(float4*)&ws[j * 4] = *(const float4*)&Wt_in[k * D_HID + d0 + dd];
    }
    __syncthreads();
    int tn = tid / 16;
    int td = tid % 16;
    float acc[4][4] = {};
    for (int k0 = 0; k0 < 96; k0 += 4) {
        float4 w0 = *(float4*)&ws[(k0 + 0) * 64 + td * 4];
        float4 w1 = *(float4*)&ws[(k0 + 1) * 64 + td * 4];
        float4 w2 = *(float4*)&ws[(k0 + 2) * 64 + td * 4];
        float4 w3 = *(float4*)&ws[(k0 + 3) * 64 + td * 4];
#pragma unroll
        for (int j = 0; j < 4; j++) {
            float4 xv = *(float4*)&xs[(tn * 4 + j) * XS_LD + k0];
            acc[j][0] += xv.x * w0.x + xv.y * w1.x + xv.z * w2.x + xv.w * w3.x;
            acc[j][1] += xv.x * w0.y + xv.y * w1.y + xv.z * w2.y + xv.w * w3.y;
            acc[j][2] += xv.x * w0.z + xv.y * w1.z + xv.z * w2.z + xv.w * w3.z;
            acc[j][3] += xv.x * w0.w + xv.y * w1.w + xv.z * w2.w + xv.w * w3.w;
        }
    }
    float4 bb = *(const float4*)&b_in[d0 + td * 4];
#pragma unroll
    for (int j = 0; j < 4; j++) {
        int node = n0 + tn * 4 + j;
        if (node < N_NODES) {
            half4 s;
            s.x = (_Float16)fmaxf(acc[j][0] + bb.x, 0.f);
            s.y = (_Float16)fmaxf(acc[j][1] + bb.y, 0.f);
            s.z = (_Float16)fmaxf(acc[j][2] + bb.z, 0.f);
            s.w = (_Float16)fmaxf(acc[j][3] + bb.w, 0.f);
            *(half4*)&h16[(size_t)node * D_HID + d0 + td * 4] = s;
        }
    }
}

// ---------------------------------------------------------------------------
// MPNN step, all-fp16 state (fp32 accumulation): 16-lane groups, half8
// (16B) gathers; self term also fp16.
__global__ __launch_bounds__(256) void k_mpnn(const _Float16* __restrict__ hin16,
                                              _Float16* __restrict__ hout16,
                                              const int* __restrict__ cnt,
                                              const unsigned short* __restrict__ esrc) {
    int g = threadIdx.x >> 4;        // 16 node-groups per block
    int l = threadIdx.x & 15;        // 16 lanes x 8 halves = 256 B row
    int n = blockIdx.x * 16 + g;
    if (n >= N_NODES) return;
    int deg = cnt[n];
    int len = min(deg, CAP);
    const unsigned short* row = &esrc[(size_t)n * CAP];
    float a0[8] = {}, a1[8] = {}, a2[8] = {}, a3[8] = {};
    int i = 0;
    for (; i + 4 <= len; i += 4) {
        int e0 = row[i + 0];
        int e1 = row[i + 1];
        int e2 = row[i + 2];
        int e3 = row[i + 3];
        half8 v0 = *(const half8*)&hin16[(size_t)e0 * 128 + l * 8];
        half8 v1 = *(const half8*)&hin16[(size_t)e1 * 128 + l * 8];
        half8 v2 = *(const half8*)&hin16[(size_t)e2 * 128 + l * 8];
        half8 v3 = *(const half8*)&hin16[(size_t)e3 * 128 + l * 8];
#pragma unroll
        for (int c = 0; c < 8; c++) {
            a0[c] += (float)v0[c];
            a1[c] += (float)v1[c];
            a2[c] += (float)v2[c];
            a3[c] += (float)v3[c];
        }
    }
    for (; i < len; i++) {
        int e0 = row[i];
        half8 v0 = *(const half8*)&hin16[(size_t)e0 * 128 + l * 8];
#pragma unroll
        for (int c = 0; c < 8; c++) a0[c] += (float)v0[c];
    }
#pragma unroll
    for (int c = 0; c < 8; c++) a0[c] += a1[c] + a2[c] + a3[c];
    float invd = 1.0f / (float)max(deg, 1);
    half8 sv = *(const half8*)&hin16[(size_t)n * 128 + l * 8];
    half8 s;
#pragma unroll
    for (int c = 0; c < 8; c++)
        s[c] = (_Float16)(((float)sv[c] + a0[c] * invd) * 0.5f);
    *(half8*)&hout16[(size_t)n * 128 + l * 8] = s;
}

__device__ __forceinline__ float sigmoidf_(float v) { return 1.0f / (1.0f + expf(-v)); }

// ---------------------------------------------------------------------------
// Fused Set2Set v5: 1024 threads/block, 2 graphs/block, GEMM split-K.
// LSTM reads gpart_s directly (combined biases precomputed in LDS).
__global__ __launch_bounds__(1024) void k_s2s2(const float* __restrict__ Wt2,
                                               const float* __restrict__ b_ih,
                                               const float* __restrict__ b_hh,
                                               const _Float16* __restrict__ h16,
                                               const int* __restrict__ seg_ptr,
                                               const float* __restrict__ W_pred,
                                               const float* __restrict__ b_pred,
                                               float* __restrict__ out) {
    __shared__ __align__(16) float in_s[2 * 256];     // [row][ hh(128) | r(128) ]
    __shared__ __align__(16) float c_s[2 * 128];
    __shared__ __align__(16) float bias_s[512];
    __shared__ __align__(16) float gpart_s[2][2][512]; // [khalf][row][gate]
    __shared__ float smax_s[2][16];
    __shared__ float ssum_s[2][16];
    __shared__ __align__(16) float sr_s[2][16][128];

    int t = threadIdx.x;
    if (t < 512) {
        in_s[t] = 0.f;
        bias_s[t] = b_ih[t] + b_hh[t];
    }
    if (t < 256) c_s[t] = 0.f;

    int gate = t & 511;
    int kh   = t >> 9;              // K-half for the gates GEMM
    int row  = t >> 9;              // graph within block (attention mapping)
    int loc  = t & 511;
    int gq   = loc >> 5;            // 16 groups of 32 lanes per graph
    int l    = t & 31;
    int b    = blockIdx.x * 2 + row;
    int s0 = seg_ptr[b], s1 = seg_ptr[b + 1];

    for (int step = 0; step < 3; step++) {
        __syncthreads();
        // ---- gates GEMM, split-K: 128 iterations per thread, both rows
        {
            float acc0 = 0.f, acc1 = 0.f;
            int k0 = kh * 128;
#pragma unroll 8
            for (int k = k0; k < k0 + 128; k++) {
                float w = Wt2[k * 512 + gate];
                acc0 += in_s[k] * w;
                acc1 += in_s[256 + k] * w;
            }
            gpart_s[kh][0][gate] = acc0;
            gpart_s[kh][1][gate] = acc1;
        }
        __syncthreads();
        // ---- LSTM: reads gpart_s directly
        if (t < 256) {
            int r2 = t >> 7, ff = t & 127;
            float ig = gpart_s[0][r2][ff]       + gpart_s[1][r2][ff]       + bias_s[ff];
            float fg = gpart_s[0][r2][128 + ff] + gpart_s[1][r2][128 + ff] + bias_s[128 + ff];
            float gg = gpart_s[0][r2][256 + ff] + gpart_s[1][r2][256 + ff] + bias_s[256 + ff];
            float og = gpart_s[0][r2][384 + ff] + gpart_s[1][r2][384 + ff] + bias_s[384 + ff];
            float c = sigmoidf_(fg) * c_s[r2 * 128 + ff] + sigmoidf_(ig) * tanhf(gg);
            c_s[r2 * 128 + ff] = c;
            in_s[r2 * 256 + ff] = sigmoidf_(og) * tanhf(c);   // hh (= q)
        }
        __syncthreads();
        // ---- attention: 16 groups/graph, dual online states, fp16 h reads
        float4 q = *(float4*)&in_s[row * 256 + l * 4];
        float Ma = -INFINITY, sa = 0.f;
        float Mb = -INFINITY, sb = 0.f;
        float4 ra = make_float4(0.f, 0.f, 0.f, 0.f);
        float4 rb = make_float4(0.f, 0.f, 0.f, 0.f);
        for (int n = s0 + gq; n < s1; n += 32) {
            {
                half4 h4 = *(const half4*)&h16[(size_t)n * 128 + l * 4];
                float4 hv = make_float4((float)h4.x, (float)h4.y, (float)h4.z, (float)h4.w);
                float d = hv.x * q.x + hv.y * q.y + hv.z * q.z + hv.w * q.w;
                for (int m = 16; m >= 1; m >>= 1) d += __shfl_xor(d, m, 64);
                float nM = fmaxf(Ma, d);
                float sc = expf(Ma - nM);
                float a = expf(d - nM);
                sa = sa * sc + a;
                ra.x = ra.x * sc + a * hv.x;
                ra.y = ra.y * sc + a * hv.y;
                ra.z = ra.z * sc + a * hv.z;
                ra.w = ra.w * sc + a * hv.w;
                Ma = nM;
            }
            int n2 = n + 16;
            if (n2 < s1) {
                half4 h4 = *(const half4*)&h16[(size_t)n2 * 128 + l * 4];
                float4 hv = make_float4((float)h4.x, (float)h4.y, (float)h4.z, (float)h4.w);
                float d = hv.x * q.x + hv.y * q.y + hv.z * q.z + hv.w * q.w;
                for (int m = 16; m >= 1; m >>= 1) d += __shfl_xor(d, m, 64);
                float nM = fmaxf(Mb, d);
                float sc = expf(Mb - nM);
                float a = expf(d - nM);
                sb = sb * sc + a;
                rb.x = rb.x * sc + a * hv.x;
                rb.y = rb.y * sc + a * hv.y;
                rb.z = rb.z * sc + a * hv.z;
                rb.w = rb.w * sc + a * hv.w;
                Mb = nM;
            }
        }
        float M = fmaxf(Ma, Mb);
        float wa = (Ma > -INFINITY) ? expf(Ma - M) : 0.f;
        float wb = (Mb > -INFINITY) ? expf(Mb - M) : 0.f;
        float asum = sa * wa + sb * wb;
        float4 racc;
        racc.x = ra.x * wa + rb.x * wb;
        racc.y = ra.y * wa + rb.y * wb;
        racc.z = ra.z * wa + rb.z * wb;
        racc.w = ra.w * wa + rb.w * wb;
        if (l == 0) { smax_s[row][gq] = M; ssum_s[row][gq] = asum; }
        *(float4*)&sr_s[row][gq][l * 4] = racc;
        __syncthreads();
        if (gq == 0) {
            float Mx = -INFINITY;
#pragma unroll
            for (int i = 0; i < 16; i++) Mx = fmaxf(Mx, smax_s[row][i]);
            float4 o = make_float4(0.f, 0.f, 0.f, 0.f);
            if (Mx > -INFINITY) {
                float tot = 0.f;
                float4 osum = make_float4(0.f, 0.f, 0.f, 0.f);
#pragma unroll
                for (int i = 0; i < 16; i++) {
                    float wi = expf(smax_s[row][i] - Mx);   // -inf -> 0
                    tot += ssum_s[row][i] * wi;
                    float4 ri = *(float4*)&sr_s[row][i][l * 4];
                    osum.x += ri.x * wi; osum.y += ri.y * wi;
                    osum.z += ri.z * wi; osum.w += ri.w * wi;
                }
                float inv = 1.0f / (tot + 1e-16f);
                o.x = osum.x * inv; o.y = osum.y * inv;
                o.z = osum.z * inv; o.w = osum.w * inv;
            }
            *(float4*)&in_s[row * 256 + 128 + l * 4] = o;   // r for next step
            if (step == 2) {
                float4 wq = *(const float4*)&W_pred[l * 4];
                float4 wr = *(const float4*)&W_pred[128 + l * 4];
                float d = q.x * wq.x + q.y * wq.y + q.z * wq.z + q.w * wq.w
                        + o.x * wr.x + o.y * wr.y + o.z * wr.z + o.w * wr.w;
                for (int m = 16; m >= 1; m >>= 1) d += __shfl_xor(d, m, 64);
                if (l == 0) out[b] = d + b_pred[0];
            }
        }
    }
}

// ---------------------------------------------------------------------------
extern "C" void kernel_launch(void* const* d_in, const int* in_sizes, int n_in,
                              void* d_out, int out_size, void* d_ws, size_t ws_size,
                              hipStream_t stream) {
    const float* x      = (const float*)d_in[0];
    const int*   edge   = (const int*)d_in[1];
    const int*   batch  = (const int*)d_in[2];
    const float* W_in   = (const float*)d_in[3];
    const float* b_in   = (const float*)d_in[4];
    const float* W_ih   = (const float*)d_in[5];
    const float* W_hh   = (const float*)d_in[6];
    const float* b_ih   = (const float*)d_in[7];
    const float* b_hh   = (const float*)d_in[8];
    const float* W_pred = (const float*)d_in[9];
    const float* b_pred = (const float*)d_in[10];
    float* out = (float*)d_out;

    const int* src = edge;
    const int* dst = edge + N_EDGES;

    float* f = (float*)d_ws;
    _Float16* g0 = (_Float16*)f;          f += (size_t)N_NODES * D_HID / 2;
    _Float16* g1 = (_Float16*)f;          f += (size_t)N_NODES * D_HID / 2;
    float* Wt_in = f;                     f += D_INP * D_HID;
    float* Wt2   = f;                     f += 256 * 512;
    int* ip = (int*)f;
    int* cnt     = ip;                    ip += N_NODES;
    int* seg_ptr = ip;                    ip += N_B + 1 + 3;   // keep alignment
    unsigned short* esrc = (unsigned short*)ip;   // 50000*64*2 B

    // ---- weight prep + cnt zero + seg_ptr
    k_prep<<<768, 256, 0, stream>>>(W_in, W_ih, W_hh, batch, Wt_in, Wt2, cnt, seg_ptr);

    // ---- XCD-partitioned edge bucketing (8 blocks/chunk, dst&7 filter)
    k_bucket8<<<((N_EDGES + 255) / 256) * 8, 256, 0, stream>>>(src, dst, cnt, esrc);

    // ---- input layer (fp16 state only, coalesced Wt_in staging)
    k_ingemm<<<dim3((N_NODES + 63) / 64, 2), 256, 0, stream>>>(x, Wt_in, b_in, g0);

    // ---- 4 MPNN steps, all-fp16 state (ping-pong, ends in g0)
    int mb = (N_NODES + 15) / 16;
    k_mpnn<<<mb, 256, 0, stream>>>(g0, g1, cnt, esrc);
    k_mpnn<<<mb, 256, 0, stream>>>(g1, g0, cnt, esrc);
    k_mpnn<<<mb, 256, 0, stream>>>(g0, g1, cnt, esrc);
    k_mpnn<<<mb, 256, 0, stream>>>(g1, g0, cnt, esrc);

    // ---- fused Set2Set + head (reads fp16 g0)
    k_s2s2<<<N_B / 2, 1024, 0, stream>>>(Wt2, b_ih, b_hh, g0, seg_ptr,
                                         W_pred, b_pred, out);
}